// Round 10
// baseline (305.063 us; speedup 1.0000x reference)
//
#include <hip/hip_runtime.h>
#include <hip/hip_bf16.h>

// GCN + MultiHead GAT + TCN — bf16 MFMA pipeline with split-precision paths.
// B=16, N=1024, NFEAT=128, NHID=256, NOUT=256, H=4, DH=64.
//
// Round 9 -> 10: flash at 66us showed MfmaUtil 20 + VALUBusy 39 -> ~40% of
// cycles with NEITHER pipe issuing = the 2-barriers-per-tile stage drain
// (vmcnt(0)+barrier with no overlap). Fix: T3-minimum 2-phase double-buffer
// in flash AND all mgemm kernels: issue STAGE(buf^1, t+1) first, compute
// tile t from buf, ONE barrier per tile (compiler's vmcnt(0)-before-barrier
// now drains loads that had the whole compute phase in flight).
// Flash LDS: dbuf K hi/lo + Vt (48KB) + Pl (16KB) = 64KiB exactly (Ls aliased
// into Pl after the loop; per-wave, no barrier needed). s_setprio(1) around
// flash MFMA clusters (T5, +4-7% attn per m191).
//
// Precision plan: gemm0 plain bf16; gemm1 SPLIT hi/lo both sides (BN1
// amplifies pre-BN error ~100x); gemm2 SPLIT; flash QK^T SPLIT; flash PV
// plain (P in [0,1], sum=1); gemm3 plain. BN stats fused into gemm1/gemm3.
// MFMA: v_mfma_f32_16x16x32_bf16. A[row=l&15][k=(l>>4)*8+i], B likewise on BT
// storage, D[col=l&15][row=(l>>4)*4+reg] (m89-verified).
// LDS tiles [k/8][row][8] staged via global_load_lds(16B), per-lane permuted
// global source (m173), wave-uniform LDS base.

typedef unsigned short u16;
typedef __attribute__((ext_vector_type(8))) short short8;  // 8 bf16 = 4 VGPR
typedef __attribute__((ext_vector_type(4))) float f32x4;

static __device__ __forceinline__ float4 ld4(const float* p){ return *(const float4*)p; }
static __device__ __forceinline__ void st4(float* p, float4 v){ *(float4*)p = v; }

static __device__ __forceinline__ u16 f2bf(float f){           // RNE
  unsigned u = __builtin_bit_cast(unsigned, f);
  unsigned r = u + 0x7FFFu + ((u >> 16) & 1u);
  return (u16)(r >> 16);
}
static __device__ __forceinline__ float bf2f(u16 h){
  unsigned u = ((unsigned)h) << 16; return __builtin_bit_cast(float, u);
}
static __device__ __forceinline__ void st4bf(u16* p, u16 a, u16 b, u16 c, u16 d){
  uint2 v; v.x = (unsigned)a | ((unsigned)b << 16); v.y = (unsigned)c | ((unsigned)d << 16);
  *(uint2*)p = v;
}
static __device__ __forceinline__ f32x4 mfma16(short8 a, short8 b, f32x4 c){
  return __builtin_amdgcn_mfma_f32_16x16x32_bf16(a, b, c, 0, 0, 0);
}

// ---------------------------------------------------------------- MFMA GEMM body
// A [M][K] bf16 row-major (hi/lo), B as BT [NN][K] bf16 (hi/lo).
// Tile BM x BN, 4 waves as WR x WC grid; double-buffered LDS (2-phase).
template<int SPLIT, int K, int NN, int MODE, int AXSWAP, int BM, int BN, int WR, int WC>
static __device__ __forceinline__ void mgemm_body(
    const u16* __restrict__ Ah_, const u16* __restrict__ Al_,
    const u16* __restrict__ Bh_, const u16* __restrict__ Bl_,
    const u16* __restrict__ zbuf,
    void* __restrict__ C0v, void* __restrict__ C1v, void* __restrict__ C2v,
    const float* __restrict__ bias)
{
  constexpr int KT = K / 32;
  constexpr int WM = BM / WR, WN = BN / WC;
  constexpr int MI = WM / 16, NJ = WN / 16;
  __shared__ u16 Ah[2][BM * 32], Bh[2][BN * 32];
  __shared__ u16 Al[2][SPLIT == 3 ? BM * 32 : 8], Bl[2][SPLIT == 3 ? BN * 32 : 8];
  const int tid = threadIdx.x;
  const int n0 = (AXSWAP ? blockIdx.y : blockIdx.x) * BN;
  const int m0 = (AXSWAP ? blockIdx.x : blockIdx.y) * BM;
  const int lane = tid & 63, l15 = lane & 15, lq = lane >> 4;
  const int w = tid >> 6, wr = w / WC, wc = w % WC;

  f32x4 acc[MI][NJ] = {};

  auto STAGE = [&](int buf, int kt){
    const int k0 = kt * 32;
#pragma unroll
    for (int r = 0; r < BM / 64; ++r){
      const int slot = r * 256 + tid;
      const int row = slot & (BM - 1), kh = slot / BM;
      const int ldsoff = (r * 256 + (tid & 192)) * 8;   // wave-uniform; lane adds 16B
      const u16* asrc;
      if constexpr (MODE == 3){
        const int kz = k0 >> 8;
        const int ci0 = (k0 & 255) + kh * 8;
        const int R = m0 + row;
        const int nn = (R & 1023) + kz - 1;
        asrc = ((unsigned)nn < 1024u) ? (Ah_ + (size_t)(R + kz - 1) * 256 + ci0) : zbuf;
      } else {
        asrc = Ah_ + (size_t)(m0 + row) * K + k0 + kh * 8;
      }
      __builtin_amdgcn_global_load_lds(asrc, &Ah[buf][ldsoff], 16, 0, 0);
      if constexpr (SPLIT == 3){
        const u16* asrc2 = Al_ + (size_t)(m0 + row) * K + k0 + kh * 8;
        __builtin_amdgcn_global_load_lds(asrc2, &Al[buf][ldsoff], 16, 0, 0);
      }
    }
#pragma unroll
    for (int r = 0; r < BN / 64; ++r){
      const int slot = r * 256 + tid;
      const int row = slot & (BN - 1), kh = slot / BN;
      const int ldsoff = (r * 256 + (tid & 192)) * 8;
      const u16* bsrc = Bh_ + (size_t)(n0 + row) * K + k0 + kh * 8;
      __builtin_amdgcn_global_load_lds(bsrc, &Bh[buf][ldsoff], 16, 0, 0);
      if constexpr (SPLIT == 3){
        const u16* bsrc2 = Bl_ + (size_t)(n0 + row) * K + k0 + kh * 8;
        __builtin_amdgcn_global_load_lds(bsrc2, &Bl[buf][ldsoff], 16, 0, 0);
      }
    }
  };

  STAGE(0, 0);
  __syncthreads();                       // compiler emits vmcnt(0) drain here
  for (int kt = 0; kt < KT; ++kt){
    const int cur = kt & 1;
    if (kt + 1 < KT) STAGE(cur ^ 1, kt + 1);   // issue next tile FIRST
    short8 afh[MI], bfh[NJ], afl[MI], bfl[NJ];
#pragma unroll
    for (int f = 0; f < MI; ++f){
      afh[f] = *(const short8*)&Ah[cur][(lq * BM + wr * WM + f * 16 + l15) * 8];
      if constexpr (SPLIT == 3)
        afl[f] = *(const short8*)&Al[cur][(lq * BM + wr * WM + f * 16 + l15) * 8];
    }
#pragma unroll
    for (int f = 0; f < NJ; ++f){
      bfh[f] = *(const short8*)&Bh[cur][(lq * BN + wc * WN + f * 16 + l15) * 8];
      if constexpr (SPLIT == 3)
        bfl[f] = *(const short8*)&Bl[cur][(lq * BN + wc * WN + f * 16 + l15) * 8];
    }
#pragma unroll
    for (int fi = 0; fi < MI; ++fi)
#pragma unroll
      for (int fj = 0; fj < NJ; ++fj){
        acc[fi][fj] = mfma16(afh[fi], bfh[fj], acc[fi][fj]);
        if constexpr (SPLIT == 3){
          acc[fi][fj] = mfma16(afl[fi], bfh[fj], acc[fi][fj]);
          acc[fi][fj] = mfma16(afh[fi], bfl[fj], acc[fi][fj]);
        }
      }
    __syncthreads();                     // one barrier/tile: drains t+1 loads
  }

  const int rb = m0 + wr * WM;
  const int cb = n0 + wc * WN;
  if constexpr (MODE == 0){
    u16* H = (u16*)C0v; u16* L = (u16*)C1v;
#pragma unroll
    for (int fi = 0; fi < MI; ++fi){
      const int R = rb + fi * 16 + lq * 4;
      const int nn = R & 1023, bq = R >> 10;
#pragma unroll
      for (int fj = 0; fj < NJ; ++fj){
        const int c = cb + fj * 16 + l15;
        const size_t off = (size_t)(bq * 256 + c) * 1024 + nn;
        u16 h_[4], l_[4];
#pragma unroll
        for (int r = 0; r < 4; ++r){
          float v = acc[fi][fj][r];
          u16 hi = f2bf(v); h_[r] = hi; l_[r] = f2bf(v - bf2f(hi));
        }
        st4bf(H + off, h_[0], h_[1], h_[2], h_[3]);
        st4bf(L + off, l_[0], l_[1], l_[2], l_[3]);
      }
    }
  } else if constexpr (MODE == 1){
    // g = relu(acc+bias) -> bf16 hi/lo; fused BN1 partials (exact fp32 stats).
    u16* GH = (u16*)C0v; u16* GL = (u16*)C1v; float* PT = (float*)C2v;
    const int mb = AXSWAP ? blockIdx.x : blockIdx.y;   // 16 m-blocks of 64 rows
#pragma unroll
    for (int fj = 0; fj < NJ; ++fj){
      const int c = cb + fj * 16 + l15;          // bo-space col
      const int o = c & 255, bq = c >> 8;
      const float bs = bias[o];
      float s = 0.f, q = 0.f;
#pragma unroll
      for (int fi = 0; fi < MI; ++fi){
        const int R = rb + fi * 16 + lq * 4;     // node n
#pragma unroll
        for (int r = 0; r < 4; ++r){
          const float v = fmaxf(acc[fi][fj][r] + bs, 0.f);
          s += v; q = fmaf(v, v, q);
          const u16 hi = f2bf(v);
          const size_t off = ((size_t)bq * 1024 + R + r) * 256 + o;
          GH[off] = hi;
          GL[off] = f2bf(v - bf2f(hi));
        }
      }
      // WR==1: one wave covers all 64 rows of this col; fold lq groups.
      s += __shfl_xor(s, 16, 64); s += __shfl_xor(s, 32, 64);
      q += __shfl_xor(q, 16, 64); q += __shfl_xor(q, 32, 64);
      if (lq == 0){
        PT[mb * 4096 + c]         = s;
        PT[65536 + mb * 4096 + c] = q;
      }
    }
  } else if constexpr (MODE == 2){
    u16* H = (u16*)C0v; u16* L = (u16*)C1v; u16* T = (u16*)C2v;
#pragma unroll
    for (int fi = 0; fi < MI; ++fi){
      const int R = rb + fi * 16 + lq * 4;
#pragma unroll
      for (int fj = 0; fj < NJ; ++fj){
        const int c = cb + fj * 16 + l15;
        u16 h_[4];
#pragma unroll
        for (int r = 0; r < 4; ++r){
          float v = acc[fi][fj][r];
          u16 hi = f2bf(v); h_[r] = hi;
          H[(size_t)(R + r) * 256 + c] = hi;
          L[(size_t)(R + r) * 256 + c] = f2bf(v - bf2f(hi));
        }
        st4bf(T + (size_t)c * 16384 + R, h_[0], h_[1], h_[2], h_[3]);
      }
    }
  } else {
    // y = acc + conv_b (fp32, pre-relu: BN2 stats are over y); fused partials.
    float* Y = (float*)C0v; float* PT = (float*)C2v;
    const int slot = blockIdx.y * 2 + wr;        // 256 row-slots of 64 rows
#pragma unroll
    for (int fj = 0; fj < NJ; ++fj){
      const int c = cb + fj * 16 + l15;
      const float bs = bias[c];
      float s = 0.f, q = 0.f;
#pragma unroll
      for (int fi = 0; fi < MI; ++fi){
        const int R = rb + fi * 16 + lq * 4;
#pragma unroll
        for (int r = 0; r < 4; ++r){
          const float v = acc[fi][fj][r] + bs;
          s += v; q = fmaf(v, v, q);
          Y[(size_t)(R + r) * 256 + c] = v;
        }
      }
      s += __shfl_xor(s, 16, 64); s += __shfl_xor(s, 32, 64);
      q += __shfl_xor(q, 16, 64); q += __shfl_xor(q, 32, 64);
      if (lq == 0){
        PT[slot * 256 + c]         = s;
        PT[65536 + slot * 256 + c] = q;
      }
    }
  }
}

// Non-template wrappers (hipcc drops stubs for template __global__ in .so).
__global__ __launch_bounds__(256) void gemm0_k(
    const u16* __restrict__ Ah_, const u16* __restrict__ Bh_,
    const u16* __restrict__ zbuf, void* __restrict__ C0, void* __restrict__ C1)
{ mgemm_body<1, 128, 256, 0, 0, 128, 64, 2, 2>(Ah_, nullptr, Bh_, nullptr, zbuf, C0, C1, nullptr, nullptr); }

__global__ __launch_bounds__(256) void gemm1_k(
    const u16* __restrict__ Ah_, const u16* __restrict__ Al_,
    const u16* __restrict__ Bh_, const u16* __restrict__ Bl_,
    const u16* __restrict__ zbuf, void* __restrict__ C0, void* __restrict__ C1,
    void* __restrict__ C2, const float* __restrict__ bias)
{ mgemm_body<3, 1024, 4096, 1, 1, 64, 128, 1, 4>(Ah_, Al_, Bh_, Bl_, zbuf, C0, C1, C2, bias); }

__global__ __launch_bounds__(256) void gemm2_k(
    const u16* __restrict__ Ah_, const u16* __restrict__ Al_,
    const u16* __restrict__ Bh_, const u16* __restrict__ Bl_,
    const u16* __restrict__ zbuf,
    void* __restrict__ C0, void* __restrict__ C1, void* __restrict__ C2)
{ mgemm_body<3, 256, 256, 2, 0, 128, 64, 2, 2>(Ah_, Al_, Bh_, Bl_, zbuf, C0, C1, C2, nullptr); }

__global__ __launch_bounds__(256) void gemm3_k(
    const u16* __restrict__ Ah_, const u16* __restrict__ Bh_,
    const u16* __restrict__ zbuf, void* __restrict__ C0, void* __restrict__ C2,
    const float* __restrict__ bias)
{ mgemm_body<1, 768, 256, 3, 0, 128, 64, 2, 2>(Ah_, nullptr, Bh_, nullptr, zbuf, C0, nullptr, C2, bias); }

// ---------------------------------------------------------------- flash GAT (MFMA)
// Grid 512, b = bid&15 (xcd = b%8), k_ = bid>>4, h = k_>>3, qo = k_&7.
// Block = 128 q-rows, 4 waves x 32 rows (mf=2). Double-buffered K/V staging
// (2-phase): one barrier per kv-tile. LDS = 48KB dbuf + 16KB Pl = 64KiB.
// p = exp(s-40) exact (e <= max||hp||^2 ~50 by Cauchy-Schwarz, diag >= 0);
// P per-wave LDS [kk][q32][8]; swapped PV out^T = Vt x P; Ls aliased into Pl.
__global__ __launch_bounds__(256) void flash(
    const u16* __restrict__ hp_hi, const u16* __restrict__ hp_lo,
    const u16* __restrict__ hpT, u16* __restrict__ ao)
{
  __shared__ u16 Khi[2][4096], Klo[2][4096], Vt[2][4096];
  __shared__ u16 Pl[4][2048];
  const int tid = threadIdx.x;
  const int lane = tid & 63, l15 = lane & 15, lq = lane >> 4, w = tid >> 6;
  const int bid = blockIdx.x;
  const int b = bid & 15, k_ = bid >> 4, h = k_ >> 3, qo = k_ & 7;
  const size_t qrow0 = (size_t)b * 1024 + qo * 128 + w * 32;

  short8 qh[2][2], ql[2][2];
#pragma unroll
  for (int mf = 0; mf < 2; ++mf)
#pragma unroll
    for (int ks = 0; ks < 2; ++ks){
      const size_t off = (qrow0 + mf * 16 + l15) * 256 + h * 64 + ks * 32 + lq * 8;
      qh[mf][ks] = *(const short8*)(hp_hi + off);
      ql[mf][ks] = *(const short8*)(hp_lo + off);
    }

  auto STAGE = [&](int buf, int kt){
    const int kv0 = kt * 64;
#pragma unroll
    for (int r = 0; r < 2; ++r){
      const int slot = r * 256 + tid;
      const int g1 = slot >> 6, g2 = slot & 63;     // [g1][g2] of 8x64
      const int ldsoff = (r * 256 + (tid & 192)) * 8;
      const u16* ksrc = hp_hi + ((size_t)b * 1024 + kv0 + g2) * 256 + h * 64 + g1 * 8;
      __builtin_amdgcn_global_load_lds(ksrc, &Khi[buf][ldsoff], 16, 0, 0);
      const u16* ksrc2 = hp_lo + ((size_t)b * 1024 + kv0 + g2) * 256 + h * 64 + g1 * 8;
      __builtin_amdgcn_global_load_lds(ksrc2, &Klo[buf][ldsoff], 16, 0, 0);
      const u16* vsrc = hpT + (size_t)(h * 64 + g2) * 16384 + b * 1024 + kv0 + g1 * 8;
      __builtin_amdgcn_global_load_lds(vsrc, &Vt[buf][ldsoff], 16, 0, 0);
    }
  };

  f32x4 o_[4][2] = {};   // out^T acc: [df][qf]
  float ls[8] = {};      // row-sum partials: [mf*4+r]

  STAGE(0, 0);
  __syncthreads();                       // vmcnt(0) drain emitted by compiler
  for (int kt = 0; kt < 16; ++kt){
    const int cur = kt & 1;
    if (kt < 15) STAGE(cur ^ 1, kt + 1); // issue next tile FIRST

    // QK^T + softmax numerator + P write
#pragma unroll
    for (int nf = 0; nf < 4; ++nf){
      short8 kf[2], kg[2];
#pragma unroll
      for (int ks = 0; ks < 2; ++ks){
        kf[ks] = *(const short8*)&Khi[cur][((ks * 4 + lq) * 64 + nf * 16 + l15) * 8];
        kg[ks] = *(const short8*)&Klo[cur][((ks * 4 + lq) * 64 + nf * 16 + l15) * 8];
      }
      const int kv = nf * 16 + l15;
#pragma unroll
      for (int mf = 0; mf < 2; ++mf){
        f32x4 s = {};
        __builtin_amdgcn_s_setprio(1);
#pragma unroll
        for (int ks = 0; ks < 2; ++ks){
          s = mfma16(qh[mf][ks], kf[ks], s);
          s = mfma16(ql[mf][ks], kf[ks], s);
          s = mfma16(qh[mf][ks], kg[ks], s);
        }
        __builtin_amdgcn_s_setprio(0);
        const int qb = mf * 16 + lq * 4;
        const int base = ((kv >> 3) * 32 + qb) * 8 + (kv & 7);
#pragma unroll
        for (int r = 0; r < 4; ++r){
          float v = s[r];
          v = v > 0.f ? v : 0.2f * v;                 // LeakyReLU(0.2)
          const float p = __expf(v - 40.f);           // fixed-shift numerator
          ls[mf * 4 + r] += p;
          Pl[w][base + r * 8] = f2bf(p);
        }
      }
    }

    // swapped PV: out^T[d][q] += A(V^T) x B(P as BT [q32][kv])
#pragma unroll
    for (int ks = 0; ks < 2; ++ks){
      short8 va[4], pf[2];
#pragma unroll
      for (int f = 0; f < 4; ++f)
        va[f] = *(const short8*)&Vt[cur][((ks * 4 + lq) * 64 + f * 16 + l15) * 8];
#pragma unroll
      for (int f = 0; f < 2; ++f)
        pf[f] = *(const short8*)&Pl[w][((ks * 4 + lq) * 32 + f * 16 + l15) * 8];
      __builtin_amdgcn_s_setprio(1);
#pragma unroll
      for (int df = 0; df < 4; ++df)
#pragma unroll
        for (int qf = 0; qf < 2; ++qf)
          o_[df][qf] = mfma16(va[df], pf[qf], o_[df][qf]);
      __builtin_amdgcn_s_setprio(0);
    }
    __syncthreads();                     // one barrier/tile: drains t+1 loads
  }

  // row-sum reduce across l15 groups; redistribute via Ls aliased into Pl[w]
  // (per-wave region, wave-synchronous: no block barrier needed).
#pragma unroll
  for (int mask = 1; mask < 16; mask <<= 1)
#pragma unroll
    for (int i = 0; i < 8; ++i)
      ls[i] += __shfl_xor(ls[i], mask, 64);
  float* LsF = (float*)&Pl[w][0];
  if (l15 == 0){
#pragma unroll
    for (int mf = 0; mf < 2; ++mf)
#pragma unroll
      for (int r = 0; r < 4; ++r)
        LsF[mf * 16 + lq * 4 + r] = ls[mf * 4 + r];
  }
  float inv[2];
#pragma unroll
  for (int qf = 0; qf < 2; ++qf) inv[qf] = 1.0f / LsF[qf * 16 + l15];

#pragma unroll
  for (int qf = 0; qf < 2; ++qf)
#pragma unroll
    for (int df = 0; df < 4; ++df){
      const size_t addr = (qrow0 + qf * 16 + l15) * 256 + h * 64 + df * 16 + lq * 4;
      st4bf(ao + addr,
            f2bf(o_[df][qf][0] * inv[qf]), f2bf(o_[df][qf][1] * inv[qf]),
            f2bf(o_[df][qf][2] * inv[qf]), f2bf(o_[df][qf][3] * inv[qf]));
    }
}

// ---------------------------------------------------------------- BN helpers
// Fold 256 partial slots (layout: sum[i*256+t], sumsq at +65536) -> prm.
__global__ __launch_bounds__(256) void bn_final(const float* __restrict__ part,
                                                const float* __restrict__ gamma,
                                                const float* __restrict__ beta,
                                                float* __restrict__ prm)
{
  const int t = threadIdx.x;
  float s = 0.f, q = 0.f;
#pragma unroll 8
  for (int i = 0; i < 256; ++i){ s += part[i * 256 + t]; q += part[65536 + i * 256 + t]; }
  const float mu = s * (1.f / 16384.f);
  const float var = q * (1.f / 16384.f) - mu * mu;
  prm[t] = mu;
  prm[256 + t] = rsqrtf(var + 1e-5f) * gamma[t];
  prm[512 + t] = beta[t];
}

// BN1 apply + relu: reads g as bf16 hi/lo, emits h hi/lo.
__global__ __launch_bounds__(256) void bn_apply_split(
    const u16* __restrict__ GH, const u16* __restrict__ GL,
    u16* __restrict__ H, u16* __restrict__ L, const float* __restrict__ prm)
{
  const int idx = blockIdx.x * 256 + threadIdx.x;
  const size_t off = (size_t)idx * 4;
  const int o = (int)(off & 255);
  const uint2 hv = *(const uint2*)(GH + off);
  const uint2 lv = *(const uint2*)(GL + off);
  const float4 m = ld4(prm + o), rs = ld4(prm + 256 + o), bt = ld4(prm + 512 + o);
  float x0 = bf2f((u16)(hv.x & 0xffff)) + bf2f((u16)(lv.x & 0xffff));
  float x1 = bf2f((u16)(hv.x >> 16))    + bf2f((u16)(lv.x >> 16));
  float x2 = bf2f((u16)(hv.y & 0xffff)) + bf2f((u16)(lv.y & 0xffff));
  float x3 = bf2f((u16)(hv.y >> 16))    + bf2f((u16)(lv.y >> 16));
  u16 h_[4], l_[4];
  float v;
  v = fmaxf(fmaf(x0 - m.x, rs.x, bt.x), 0.f); h_[0] = f2bf(v); l_[0] = f2bf(v - bf2f(h_[0]));
  v = fmaxf(fmaf(x1 - m.y, rs.y, bt.y), 0.f); h_[1] = f2bf(v); l_[1] = f2bf(v - bf2f(h_[1]));
  v = fmaxf(fmaf(x2 - m.z, rs.z, bt.z), 0.f); h_[2] = f2bf(v); l_[2] = f2bf(v - bf2f(h_[2]));
  v = fmaxf(fmaf(x3 - m.w, rs.w, bt.w), 0.f); h_[3] = f2bf(v); l_[3] = f2bf(v - bf2f(h_[3]));
  st4bf(H + off, h_[0], h_[1], h_[2], h_[3]);
  st4bf(L + off, l_[0], l_[1], l_[2], l_[3]);
}

// BN2 apply + relu, fp32 in-place
__global__ __launch_bounds__(256) void bn_apply(const float* __restrict__ in,
                                                float* __restrict__ outp,
                                                const float* __restrict__ prm)
{
  const int idx = blockIdx.x * 256 + threadIdx.x;
  const size_t off = (size_t)idx * 8;
  const int o = (int)(off & 255);
  const float4 x0 = ld4(in + off),      x1 = ld4(in + off + 4);
  const float4 m0 = ld4(prm + o),       m1 = ld4(prm + o + 4);
  const float4 r0 = ld4(prm + 256 + o), r1 = ld4(prm + 256 + o + 4);
  const float4 b0 = ld4(prm + 512 + o), b1 = ld4(prm + 512 + o + 4);
  float4 y0, y1;
  y0.x = fmaxf(fmaf(x0.x - m0.x, r0.x, b0.x), 0.f);
  y0.y = fmaxf(fmaf(x0.y - m0.y, r0.y, b0.y), 0.f);
  y0.z = fmaxf(fmaf(x0.z - m0.z, r0.z, b0.z), 0.f);
  y0.w = fmaxf(fmaf(x0.w - m0.w, r0.w, b0.w), 0.f);
  y1.x = fmaxf(fmaf(x1.x - m1.x, r1.x, b1.x), 0.f);
  y1.y = fmaxf(fmaf(x1.y - m1.y, r1.y, b1.y), 0.f);
  y1.z = fmaxf(fmaf(x1.z - m1.z, r1.z, b1.z), 0.f);
  y1.w = fmaxf(fmaf(x1.w - m1.w, r1.w, b1.w), 0.f);
  st4(outp + off, y0);
  st4(outp + off + 4, y1);
}

// ---------------------------------------------------------------- pack / convert
__global__ __launch_bounds__(256) void pack_w(
    const float* __restrict__ x, const float* __restrict__ adj,
    const float* __restrict__ gcw, const float* __restrict__ gatw,
    const float* __restrict__ convw,
    u16* __restrict__ xbf, u16* __restrict__ adjh, u16* __restrict__ adjl,
    u16* __restrict__ w0t, u16* __restrict__ w2th, u16* __restrict__ w2tl,
    u16* __restrict__ cwt, u16* __restrict__ zb)
{
  const int idx = blockIdx.x * 256 + threadIdx.x;
  if (idx < 2097152) xbf[idx] = f2bf(x[idx]);
  if (idx < 1048576){
    const float v = adj[idx];
    const u16 hi = f2bf(v);
    adjh[idx] = hi; adjl[idx] = f2bf(v - bf2f(hi));
  }
  if (idx < 32768){
    const int o = idx >> 7, f = idx & 127;
    w0t[idx] = f2bf(gcw[f * 256 + o]);
  }
  if (idx < 65536){
    const int c = idx >> 8, f = idx & 255;
    const float v = gatw[(c >> 6) * 16384 + f * 64 + (c & 63)];
    const u16 hi = f2bf(v);
    w2th[idx] = hi; w2tl[idx] = f2bf(v - bf2f(hi));
  }
  if (idx < 196608){
    const int co = idx / 768, k = idx - co * 768;
    const int kz = k >> 8, ci = k & 255;
    cwt[idx] = f2bf(convw[co * 768 + ci * 3 + kz]);
  }
  if (idx < 2048) zb[idx] = 0;
}

// ---------------------------------------------------------------- launch
extern "C" void kernel_launch(void* const* d_in, const int* in_sizes, int n_in,
                              void* d_out, int out_size, void* d_ws, size_t ws_size,
                              hipStream_t stream)
{
  const float* x     = (const float*)d_in[0];
  const float* adj   = (const float*)d_in[1];
  const float* gc_w  = (const float*)d_in[2];
  const float* gc_b  = (const float*)d_in[3];
  const float* bn1g  = (const float*)d_in[4];
  const float* bn1b  = (const float*)d_in[5];
  const float* gatw  = (const float*)d_in[6];
  const float* convw = (const float*)d_in[7];
  const float* convb = (const float*)d_in[8];
  const float* bn2g  = (const float*)d_in[9];
  const float* bn2b  = (const float*)d_in[10];
  char* ws  = (char*)d_ws;
  char* out = (char*)d_out;

  // ws layout (bytes), total ~26.4 MB:
  u16* h1t_hi = (u16*)(ws + 0);              // 8 MB  [bo][node]   (later: h_hi, then ao)
  u16* h1t_lo = (u16*)(ws + 8388608);        // 8 MB               (later: h_lo)
  u16* x_bf   = (u16*)(ws + 16777216);       // 4 MB               (later: hpT 8MB @16M)
  u16* adj_hi = (u16*)(ws + 20971520);       // 2 MB
  u16* adj_lo = (u16*)(ws + 23068672);       // 2 MB
  u16* hpT    = (u16*)(ws + 16777216);       // 8 MB (aliases x_bf+adj; live after both die)
  u16* w0t    = (u16*)(ws + 25165824);       // 64 KB
  u16* w2th   = (u16*)(ws + 25231360);       // 128 KB
  u16* w2tl   = (u16*)(ws + 25362432);       // 128 KB
  u16* cwt    = (u16*)(ws + 25493504);       // 384 KB
  u16* zbuf   = (u16*)(ws + 25886720);       // 4 KB zeros
  float* P1   = (float*)(ws + 25890816);     // 512 KB bn partial slots (sum | sumsq)
  float* PR1  = (float*)(ws + 26415104);     // 3 KB
  float* PR2  = (float*)(ws + 26419200);     // 3 KB
  // aliases into ws/out across phases:
  u16* h_hi  = (u16*)(ws + 0);
  u16* h_lo  = (u16*)(ws + 8388608);
  u16* ao    = (u16*)(ws + 0);
  u16* g_hi  = (u16*)out;                    // gemm1 out hi (8 MB), dead after bn_apply_split
  u16* g_lo  = (u16*)(out + 8388608);        // gemm1 out lo (8 MB)
  u16* hp_hi = (u16*)out;                    // gemm2 out, dead after flash
  u16* hp_lo = (u16*)(out + 8388608);
  float* y   = (float*)out;                  // gemm3 out -> bn2 in-place -> final

  pack_w<<<8192, 256, 0, stream>>>(x, adj, gc_w, gatw, convw,
                                   x_bf, adj_hi, adj_lo, w0t, w2th, w2tl, cwt, zbuf);
  // gemm0: x_bf @ w0t -> h1t hi/lo   (128x64 tiles, 512 blocks)
  gemm0_k<<<dim3(4, 128), 256, 0, stream>>>(x_bf, w0t, zbuf, h1t_hi, h1t_lo);
  // gemm1 (split): adj @ h1t -> g hi/lo (+gc_b, relu) + BN1 partials. m on x.
  gemm1_k<<<dim3(16, 32), 256, 0, stream>>>(adj_hi, adj_lo, h1t_hi, h1t_lo, zbuf,
                                            g_hi, g_lo, P1, gc_b);
  bn_final<<<1, 256, 0, stream>>>(P1, bn1g, bn1b, PR1);
  bn_apply_split<<<4096, 256, 0, stream>>>(g_hi, g_lo, h_hi, h_lo, PR1);
  // gemm2 (split): h @ w2t -> hp hi/lo + hpT   (128x64 tiles, 512 blocks)
  gemm2_k<<<dim3(4, 128), 256, 0, stream>>>(h_hi, h_lo, w2th, w2tl, zbuf, hp_hi, hp_lo, hpT);
  // flash GAT (512 blocks x 128 q-rows, dbuf 2-phase)
  flash<<<512, 256, 0, stream>>>(hp_hi, hp_lo, hpT, ao);
  // gemm3: im2col(ao) @ cwt -> y fp32 (+conv_b) + BN2 partials
  gemm3_k<<<dim3(4, 128), 256, 0, stream>>>(ao, cwt, zbuf, y, P1, convb);
  bn_final<<<1, 256, 0, stream>>>(P1, bn2g, bn2b, PR2);
  bn_apply<<<2048, 256, 0, stream>>>(y, y, PR2);
}

// Round 11
// 294.945 us; speedup vs baseline: 1.0343x; 1.0343x over previous
//
#include <hip/hip_runtime.h>
#include <hip/hip_bf16.h>

// GCN + MultiHead GAT + TCN — bf16 MFMA pipeline with split-precision paths.
// B=16, N=1024, NFEAT=128, NHID=256, NOUT=256, H=4, DH=64.
//
// Round 10 -> 11: gemm1 pinned at ~68us across 3 schedules (MfmaUtil 15%,
// both pipes idle 68%): its 26 GF-equiv through 36MB is structural. Fix by
// REASSOCIATION: g = adj@(x@W0) = (adj@x)@W0.
//   adjx  = adj@xT  split-3: 12.9 GF-equiv (was 25.8), out ax hi/lo 8MB
//   gemm1n= ax@W0   split-3:  3.2 GF-equiv, K=128, fused BN1 partials
// Old gemm0/gemm1 removed. Precision IMPROVES: old path's dominant error was
// plain-bf16 gemm0; new path is split-3 end-to-end.
//
// Precision plan: adjx SPLIT (adj,x hi/lo); gemm1n SPLIT (ax,W0 hi/lo);
// gemm2 SPLIT; flash QK^T SPLIT; flash PV plain (P in [0,1], sum=1);
// gemm3 plain. BN stats fused into gemm1n/gemm3 epilogues (fp32-exact).
// MFMA: v_mfma_f32_16x16x32_bf16. A[row=l&15][k=(l>>4)*8+i], B likewise on BT
// storage, D[col=l&15][row=(l>>4)*4+reg] (m89-verified).
// All tiled kernels: 2-phase double-buffered LDS staging via
// global_load_lds(16B), per-lane permuted global source, wave-uniform base.

typedef unsigned short u16;
typedef __attribute__((ext_vector_type(8))) short short8;  // 8 bf16 = 4 VGPR
typedef __attribute__((ext_vector_type(4))) float f32x4;

static __device__ __forceinline__ float4 ld4(const float* p){ return *(const float4*)p; }
static __device__ __forceinline__ void st4(float* p, float4 v){ *(float4*)p = v; }

static __device__ __forceinline__ u16 f2bf(float f){           // RNE
  unsigned u = __builtin_bit_cast(unsigned, f);
  unsigned r = u + 0x7FFFu + ((u >> 16) & 1u);
  return (u16)(r >> 16);
}
static __device__ __forceinline__ float bf2f(u16 h){
  unsigned u = ((unsigned)h) << 16; return __builtin_bit_cast(float, u);
}
static __device__ __forceinline__ void st4bf(u16* p, u16 a, u16 b, u16 c, u16 d){
  uint2 v; v.x = (unsigned)a | ((unsigned)b << 16); v.y = (unsigned)c | ((unsigned)d << 16);
  *(uint2*)p = v;
}
static __device__ __forceinline__ f32x4 mfma16(short8 a, short8 b, f32x4 c){
  return __builtin_amdgcn_mfma_f32_16x16x32_bf16(a, b, c, 0, 0, 0);
}

// ---------------------------------------------------------------- MFMA GEMM body
// A [M][K] bf16 row-major (hi/lo), B as BT [NN][K] bf16 (hi/lo).
// Tile BM x BN, 4 waves as WR x WC grid; double-buffered LDS (2-phase).
// MODE 2: gemm2 -> hp hi/lo [R][256] + hpT (hi) [256][16384]
// MODE 3: gemm3 (im2col A, zbuf pad) -> y fp32 + conv_b + fused BN2 partials
// MODE 4: gemm1n -> g bf16 hi/lo [R][256] + relu + bias + fused BN1 partials
// MODE 5: adjx  -> ax hi/lo scatter [((c>>7)*1024 + row)*128 + (c&127)]
template<int SPLIT, int K, int NN, int MODE, int AXSWAP, int BM, int BN, int WR, int WC>
static __device__ __forceinline__ void mgemm_body(
    const u16* __restrict__ Ah_, const u16* __restrict__ Al_,
    const u16* __restrict__ Bh_, const u16* __restrict__ Bl_,
    const u16* __restrict__ zbuf,
    void* __restrict__ C0v, void* __restrict__ C1v, void* __restrict__ C2v,
    const float* __restrict__ bias)
{
  constexpr int KT = K / 32;
  constexpr int WM = BM / WR, WN = BN / WC;
  constexpr int MI = WM / 16, NJ = WN / 16;
  __shared__ u16 Ah[2][BM * 32], Bh[2][BN * 32];
  __shared__ u16 Al[2][SPLIT == 3 ? BM * 32 : 8], Bl[2][SPLIT == 3 ? BN * 32 : 8];
  const int tid = threadIdx.x;
  const int n0 = (AXSWAP ? blockIdx.y : blockIdx.x) * BN;
  const int m0 = (AXSWAP ? blockIdx.x : blockIdx.y) * BM;
  const int lane = tid & 63, l15 = lane & 15, lq = lane >> 4;
  const int w = tid >> 6, wr = w / WC, wc = w % WC;

  f32x4 acc[MI][NJ] = {};

  auto STAGE = [&](int buf, int kt){
    const int k0 = kt * 32;
#pragma unroll
    for (int r = 0; r < BM / 64; ++r){
      const int slot = r * 256 + tid;
      const int row = slot & (BM - 1), kh = slot / BM;
      const int ldsoff = (r * 256 + (tid & 192)) * 8;   // wave-uniform; lane adds 16B
      const u16* asrc;
      if constexpr (MODE == 3){
        const int kz = k0 >> 8;
        const int ci0 = (k0 & 255) + kh * 8;
        const int R = m0 + row;
        const int nn = (R & 1023) + kz - 1;
        asrc = ((unsigned)nn < 1024u) ? (Ah_ + (size_t)(R + kz - 1) * 256 + ci0) : zbuf;
      } else {
        asrc = Ah_ + (size_t)(m0 + row) * K + k0 + kh * 8;
      }
      __builtin_amdgcn_global_load_lds(asrc, &Ah[buf][ldsoff], 16, 0, 0);
      if constexpr (SPLIT == 3){
        const u16* asrc2 = Al_ + (size_t)(m0 + row) * K + k0 + kh * 8;
        __builtin_amdgcn_global_load_lds(asrc2, &Al[buf][ldsoff], 16, 0, 0);
      }
    }
#pragma unroll
    for (int r = 0; r < BN / 64; ++r){
      const int slot = r * 256 + tid;
      const int row = slot & (BN - 1), kh = slot / BN;
      const int ldsoff = (r * 256 + (tid & 192)) * 8;
      const u16* bsrc = Bh_ + (size_t)(n0 + row) * K + k0 + kh * 8;
      __builtin_amdgcn_global_load_lds(bsrc, &Bh[buf][ldsoff], 16, 0, 0);
      if constexpr (SPLIT == 3){
        const u16* bsrc2 = Bl_ + (size_t)(n0 + row) * K + k0 + kh * 8;
        __builtin_amdgcn_global_load_lds(bsrc2, &Bl[buf][ldsoff], 16, 0, 0);
      }
    }
  };

  STAGE(0, 0);
  __syncthreads();                       // compiler emits vmcnt(0) drain here
  for (int kt = 0; kt < KT; ++kt){
    const int cur = kt & 1;
    if (kt + 1 < KT) STAGE(cur ^ 1, kt + 1);   // issue next tile FIRST
    short8 afh[MI], bfh[NJ], afl[MI], bfl[NJ];
#pragma unroll
    for (int f = 0; f < MI; ++f){
      afh[f] = *(const short8*)&Ah[cur][(lq * BM + wr * WM + f * 16 + l15) * 8];
      if constexpr (SPLIT == 3)
        afl[f] = *(const short8*)&Al[cur][(lq * BM + wr * WM + f * 16 + l15) * 8];
    }
#pragma unroll
    for (int f = 0; f < NJ; ++f){
      bfh[f] = *(const short8*)&Bh[cur][(lq * BN + wc * WN + f * 16 + l15) * 8];
      if constexpr (SPLIT == 3)
        bfl[f] = *(const short8*)&Bl[cur][(lq * BN + wc * WN + f * 16 + l15) * 8];
    }
#pragma unroll
    for (int fi = 0; fi < MI; ++fi)
#pragma unroll
      for (int fj = 0; fj < NJ; ++fj){
        acc[fi][fj] = mfma16(afh[fi], bfh[fj], acc[fi][fj]);
        if constexpr (SPLIT == 3){
          acc[fi][fj] = mfma16(afl[fi], bfh[fj], acc[fi][fj]);
          acc[fi][fj] = mfma16(afh[fi], bfl[fj], acc[fi][fj]);
        }
      }
    __syncthreads();                     // one barrier/tile: drains t+1 loads
  }

  const int rb = m0 + wr * WM;
  const int cb = n0 + wc * WN;
  if constexpr (MODE == 2){
    u16* H = (u16*)C0v; u16* L = (u16*)C1v; u16* T = (u16*)C2v;
#pragma unroll
    for (int fi = 0; fi < MI; ++fi){
      const int R = rb + fi * 16 + lq * 4;
#pragma unroll
      for (int fj = 0; fj < NJ; ++fj){
        const int c = cb + fj * 16 + l15;
        u16 h_[4];
#pragma unroll
        for (int r = 0; r < 4; ++r){
          float v = acc[fi][fj][r];
          u16 hi = f2bf(v); h_[r] = hi;
          H[(size_t)(R + r) * 256 + c] = hi;
          L[(size_t)(R + r) * 256 + c] = f2bf(v - bf2f(hi));
        }
        st4bf(T + (size_t)c * 16384 + R, h_[0], h_[1], h_[2], h_[3]);
      }
    }
  } else if constexpr (MODE == 3){
    // y = acc + conv_b (fp32, pre-relu: BN2 stats are over y); fused partials.
    float* Y = (float*)C0v; float* PT = (float*)C2v;
    const int slot = blockIdx.y * 2 + wr;        // 256 row-slots of 64 rows
#pragma unroll
    for (int fj = 0; fj < NJ; ++fj){
      const int c = cb + fj * 16 + l15;
      const float bs = bias[c];
      float s = 0.f, q = 0.f;
#pragma unroll
      for (int fi = 0; fi < MI; ++fi){
        const int R = rb + fi * 16 + lq * 4;
#pragma unroll
        for (int r = 0; r < 4; ++r){
          const float v = acc[fi][fj][r] + bs;
          s += v; q = fmaf(v, v, q);
          Y[(size_t)(R + r) * 256 + c] = v;
        }
      }
      s += __shfl_xor(s, 16, 64); s += __shfl_xor(s, 32, 64);
      q += __shfl_xor(q, 16, 64); q += __shfl_xor(q, 32, 64);
      if (lq == 0){
        PT[slot * 256 + c]         = s;
        PT[65536 + slot * 256 + c] = q;
      }
    }
  } else if constexpr (MODE == 4){
    // g = relu(acc+bias) -> bf16 hi/lo [R][256]; fused BN1 partials.
    u16* GH = (u16*)C0v; u16* GL = (u16*)C1v; float* PT = (float*)C2v;
    const int slot = blockIdx.y * 2 + wr;        // 256 row-slots of 64 rows
#pragma unroll
    for (int fj = 0; fj < NJ; ++fj){
      const int c = cb + fj * 16 + l15;
      const float bs = bias[c];
      float s = 0.f, q = 0.f;
#pragma unroll
      for (int fi = 0; fi < MI; ++fi){
        const int R = rb + fi * 16 + lq * 4;
#pragma unroll
        for (int r = 0; r < 4; ++r){
          const float v = fmaxf(acc[fi][fj][r] + bs, 0.f);
          s += v; q = fmaf(v, v, q);
          const u16 hi = f2bf(v);
          const size_t off = (size_t)(R + r) * 256 + c;
          GH[off] = hi;
          GL[off] = f2bf(v - bf2f(hi));
        }
      }
      s += __shfl_xor(s, 16, 64); s += __shfl_xor(s, 32, 64);
      q += __shfl_xor(q, 16, 64); q += __shfl_xor(q, 32, 64);
      if (lq == 0){
        PT[slot * 256 + c]         = s;
        PT[65536 + slot * 256 + c] = q;
      }
    }
  } else {   // MODE 5: adjx -> ax hi/lo scatter [((c>>7)*1024 + row)*128 + (c&127)]
    u16* XH = (u16*)C0v; u16* XL = (u16*)C1v;
#pragma unroll
    for (int fi = 0; fi < MI; ++fi){
      const int R = rb + fi * 16 + lq * 4;
#pragma unroll
      for (int fj = 0; fj < NJ; ++fj){
        const int c = cb + fj * 16 + l15;
        const size_t base = ((size_t)(c >> 7) * 1024 + R) * 128 + (c & 127);
#pragma unroll
        for (int r = 0; r < 4; ++r){
          const float v = acc[fi][fj][r];
          const u16 hi = f2bf(v);
          XH[base + (size_t)r * 128] = hi;
          XL[base + (size_t)r * 128] = f2bf(v - bf2f(hi));
        }
      }
    }
  }
}

// Non-template wrappers (hipcc drops stubs for template __global__ in .so).
__global__ __launch_bounds__(256) void adjx_k(
    const u16* __restrict__ Ah_, const u16* __restrict__ Al_,
    const u16* __restrict__ Bh_, const u16* __restrict__ Bl_,
    const u16* __restrict__ zbuf, void* __restrict__ C0, void* __restrict__ C1)
{ mgemm_body<3, 1024, 2048, 5, 0, 64, 64, 2, 2>(Ah_, Al_, Bh_, Bl_, zbuf, C0, C1, nullptr, nullptr); }

__global__ __launch_bounds__(256) void gemm1n_k(
    const u16* __restrict__ Ah_, const u16* __restrict__ Al_,
    const u16* __restrict__ Bh_, const u16* __restrict__ Bl_,
    const u16* __restrict__ zbuf, void* __restrict__ C0, void* __restrict__ C1,
    void* __restrict__ C2, const float* __restrict__ bias)
{ mgemm_body<3, 128, 256, 4, 0, 128, 64, 2, 2>(Ah_, Al_, Bh_, Bl_, zbuf, C0, C1, C2, bias); }

__global__ __launch_bounds__(256) void gemm2_k(
    const u16* __restrict__ Ah_, const u16* __restrict__ Al_,
    const u16* __restrict__ Bh_, const u16* __restrict__ Bl_,
    const u16* __restrict__ zbuf,
    void* __restrict__ C0, void* __restrict__ C1, void* __restrict__ C2)
{ mgemm_body<3, 256, 256, 2, 0, 128, 64, 2, 2>(Ah_, Al_, Bh_, Bl_, zbuf, C0, C1, C2, nullptr); }

__global__ __launch_bounds__(256) void gemm3_k(
    const u16* __restrict__ Ah_, const u16* __restrict__ Bh_,
    const u16* __restrict__ zbuf, void* __restrict__ C0, void* __restrict__ C2,
    const float* __restrict__ bias)
{ mgemm_body<1, 768, 256, 3, 0, 128, 64, 2, 2>(Ah_, nullptr, Bh_, nullptr, zbuf, C0, nullptr, C2, bias); }

// ---------------------------------------------------------------- flash GAT (MFMA)
// Grid 512, b = bid&15 (xcd = b%8), k_ = bid>>4, h = k_>>3, qo = k_&7.
// Block = 128 q-rows, 4 waves x 32 rows (mf=2). Double-buffered K/V staging
// (2-phase): one barrier per kv-tile. LDS = 48KB dbuf + 16KB Pl = 64KiB.
// p = exp(s-40) exact (e <= max||hp||^2 ~50 by Cauchy-Schwarz, diag >= 0);
// P per-wave LDS [kk][q32][8]; swapped PV out^T = Vt x P; Ls aliased into Pl.
__global__ __launch_bounds__(256) void flash(
    const u16* __restrict__ hp_hi, const u16* __restrict__ hp_lo,
    const u16* __restrict__ hpT, u16* __restrict__ ao)
{
  __shared__ u16 Khi[2][4096], Klo[2][4096], Vt[2][4096];
  __shared__ u16 Pl[4][2048];
  const int tid = threadIdx.x;
  const int lane = tid & 63, l15 = lane & 15, lq = lane >> 4, w = tid >> 6;
  const int bid = blockIdx.x;
  const int b = bid & 15, k_ = bid >> 4, h = k_ >> 3, qo = k_ & 7;
  const size_t qrow0 = (size_t)b * 1024 + qo * 128 + w * 32;

  short8 qh[2][2], ql[2][2];
#pragma unroll
  for (int mf = 0; mf < 2; ++mf)
#pragma unroll
    for (int ks = 0; ks < 2; ++ks){
      const size_t off = (qrow0 + mf * 16 + l15) * 256 + h * 64 + ks * 32 + lq * 8;
      qh[mf][ks] = *(const short8*)(hp_hi + off);
      ql[mf][ks] = *(const short8*)(hp_lo + off);
    }

  auto STAGE = [&](int buf, int kt){
    const int kv0 = kt * 64;
#pragma unroll
    for (int r = 0; r < 2; ++r){
      const int slot = r * 256 + tid;
      const int g1 = slot >> 6, g2 = slot & 63;     // [g1][g2] of 8x64
      const int ldsoff = (r * 256 + (tid & 192)) * 8;
      const u16* ksrc = hp_hi + ((size_t)b * 1024 + kv0 + g2) * 256 + h * 64 + g1 * 8;
      __builtin_amdgcn_global_load_lds(ksrc, &Khi[buf][ldsoff], 16, 0, 0);
      const u16* ksrc2 = hp_lo + ((size_t)b * 1024 + kv0 + g2) * 256 + h * 64 + g1 * 8;
      __builtin_amdgcn_global_load_lds(ksrc2, &Klo[buf][ldsoff], 16, 0, 0);
      const u16* vsrc = hpT + (size_t)(h * 64 + g2) * 16384 + b * 1024 + kv0 + g1 * 8;
      __builtin_amdgcn_global_load_lds(vsrc, &Vt[buf][ldsoff], 16, 0, 0);
    }
  };

  f32x4 o_[4][2] = {};   // out^T acc: [df][qf]
  float ls[8] = {};      // row-sum partials: [mf*4+r]

  STAGE(0, 0);
  __syncthreads();                       // vmcnt(0) drain emitted by compiler
  for (int kt = 0; kt < 16; ++kt){
    const int cur = kt & 1;
    if (kt < 15) STAGE(cur ^ 1, kt + 1); // issue next tile FIRST

    // QK^T + softmax numerator + P write
#pragma unroll
    for (int nf = 0; nf < 4; ++nf){
      short8 kf[2], kg[2];
#pragma unroll
      for (int ks = 0; ks < 2; ++ks){
        kf[ks] = *(const short8*)&Khi[cur][((ks * 4 + lq) * 64 + nf * 16 + l15) * 8];
        kg[ks] = *(const short8*)&Klo[cur][((ks * 4 + lq) * 64 + nf * 16 + l15) * 8];
      }
      const int kv = nf * 16 + l15;
#pragma unroll
      for (int mf = 0; mf < 2; ++mf){
        f32x4 s = {};
        __builtin_amdgcn_s_setprio(1);
#pragma unroll
        for (int ks = 0; ks < 2; ++ks){
          s = mfma16(qh[mf][ks], kf[ks], s);
          s = mfma16(ql[mf][ks], kf[ks], s);
          s = mfma16(qh[mf][ks], kg[ks], s);
        }
        __builtin_amdgcn_s_setprio(0);
        const int qb = mf * 16 + lq * 4;
        const int base = ((kv >> 3) * 32 + qb) * 8 + (kv & 7);
#pragma unroll
        for (int r = 0; r < 4; ++r){
          float v = s[r];
          v = v > 0.f ? v : 0.2f * v;                 // LeakyReLU(0.2)
          const float p = __expf(v - 40.f);           // fixed-shift numerator
          ls[mf * 4 + r] += p;
          Pl[w][base + r * 8] = f2bf(p);
        }
      }
    }

    // swapped PV: out^T[d][q] += A(V^T) x B(P as BT [q32][kv])
#pragma unroll
    for (int ks = 0; ks < 2; ++ks){
      short8 va[4], pf[2];
#pragma unroll
      for (int f = 0; f < 4; ++f)
        va[f] = *(const short8*)&Vt[cur][((ks * 4 + lq) * 64 + f * 16 + l15) * 8];
#pragma unroll
      for (int f = 0; f < 2; ++f)
        pf[f] = *(const short8*)&Pl[w][((ks * 4 + lq) * 32 + f * 16 + l15) * 8];
      __builtin_amdgcn_s_setprio(1);
#pragma unroll
      for (int df = 0; df < 4; ++df)
#pragma unroll
        for (int qf = 0; qf < 2; ++qf)
          o_[df][qf] = mfma16(va[df], pf[qf], o_[df][qf]);
      __builtin_amdgcn_s_setprio(0);
    }
    __syncthreads();                     // one barrier/tile: drains t+1 loads
  }

  // row-sum reduce across l15 groups; redistribute via Ls aliased into Pl[w]
  // (per-wave region, wave-synchronous: no block barrier needed).
#pragma unroll
  for (int mask = 1; mask < 16; mask <<= 1)
#pragma unroll
    for (int i = 0; i < 8; ++i)
      ls[i] += __shfl_xor(ls[i], mask, 64);
  float* LsF = (float*)&Pl[w][0];
  if (l15 == 0){
#pragma unroll
    for (int mf = 0; mf < 2; ++mf)
#pragma unroll
      for (int r = 0; r < 4; ++r)
        LsF[mf * 16 + lq * 4 + r] = ls[mf * 4 + r];
  }
  float inv[2];
#pragma unroll
  for (int qf = 0; qf < 2; ++qf) inv[qf] = 1.0f / LsF[qf * 16 + l15];

#pragma unroll
  for (int qf = 0; qf < 2; ++qf)
#pragma unroll
    for (int df = 0; df < 4; ++df){
      const size_t addr = (qrow0 + qf * 16 + l15) * 256 + h * 64 + df * 16 + lq * 4;
      st4bf(ao + addr,
            f2bf(o_[df][qf][0] * inv[qf]), f2bf(o_[df][qf][1] * inv[qf]),
            f2bf(o_[df][qf][2] * inv[qf]), f2bf(o_[df][qf][3] * inv[qf]));
    }
}

// ---------------------------------------------------------------- BN helpers
// Fold 256 partial slots (layout: sum[i*256+t], sumsq at +65536) -> prm.
__global__ __launch_bounds__(256) void bn_final(const float* __restrict__ part,
                                                const float* __restrict__ gamma,
                                                const float* __restrict__ beta,
                                                float* __restrict__ prm)
{
  const int t = threadIdx.x;
  float s = 0.f, q = 0.f;
#pragma unroll 8
  for (int i = 0; i < 256; ++i){ s += part[i * 256 + t]; q += part[65536 + i * 256 + t]; }
  const float mu = s * (1.f / 16384.f);
  const float var = q * (1.f / 16384.f) - mu * mu;
  prm[t] = mu;
  prm[256 + t] = rsqrtf(var + 1e-5f) * gamma[t];
  prm[512 + t] = beta[t];
}

// BN1 apply + relu: reads g as bf16 hi/lo, emits h hi/lo.
__global__ __launch_bounds__(256) void bn_apply_split(
    const u16* __restrict__ GH, const u16* __restrict__ GL,
    u16* __restrict__ H, u16* __restrict__ L, const float* __restrict__ prm)
{
  const int idx = blockIdx.x * 256 + threadIdx.x;
  const size_t off = (size_t)idx * 4;
  const int o = (int)(off & 255);
  const uint2 hv = *(const uint2*)(GH + off);
  const uint2 lv = *(const uint2*)(GL + off);
  const float4 m = ld4(prm + o), rs = ld4(prm + 256 + o), bt = ld4(prm + 512 + o);
  float x0 = bf2f((u16)(hv.x & 0xffff)) + bf2f((u16)(lv.x & 0xffff));
  float x1 = bf2f((u16)(hv.x >> 16))    + bf2f((u16)(lv.x >> 16));
  float x2 = bf2f((u16)(hv.y & 0xffff)) + bf2f((u16)(lv.y & 0xffff));
  float x3 = bf2f((u16)(hv.y >> 16))    + bf2f((u16)(lv.y >> 16));
  u16 h_[4], l_[4];
  float v;
  v = fmaxf(fmaf(x0 - m.x, rs.x, bt.x), 0.f); h_[0] = f2bf(v); l_[0] = f2bf(v - bf2f(h_[0]));
  v = fmaxf(fmaf(x1 - m.y, rs.y, bt.y), 0.f); h_[1] = f2bf(v); l_[1] = f2bf(v - bf2f(h_[1]));
  v = fmaxf(fmaf(x2 - m.z, rs.z, bt.z), 0.f); h_[2] = f2bf(v); l_[2] = f2bf(v - bf2f(h_[2]));
  v = fmaxf(fmaf(x3 - m.w, rs.w, bt.w), 0.f); h_[3] = f2bf(v); l_[3] = f2bf(v - bf2f(h_[3]));
  st4bf(H + off, h_[0], h_[1], h_[2], h_[3]);
  st4bf(L + off, l_[0], l_[1], l_[2], l_[3]);
}

// BN2 apply + relu, fp32 in-place
__global__ __launch_bounds__(256) void bn_apply(const float* __restrict__ in,
                                                float* __restrict__ outp,
                                                const float* __restrict__ prm)
{
  const int idx = blockIdx.x * 256 + threadIdx.x;
  const size_t off = (size_t)idx * 8;
  const int o = (int)(off & 255);
  const float4 x0 = ld4(in + off),      x1 = ld4(in + off + 4);
  const float4 m0 = ld4(prm + o),       m1 = ld4(prm + o + 4);
  const float4 r0 = ld4(prm + 256 + o), r1 = ld4(prm + 256 + o + 4);
  const float4 b0 = ld4(prm + 512 + o), b1 = ld4(prm + 512 + o + 4);
  float4 y0, y1;
  y0.x = fmaxf(fmaf(x0.x - m0.x, r0.x, b0.x), 0.f);
  y0.y = fmaxf(fmaf(x0.y - m0.y, r0.y, b0.y), 0.f);
  y0.z = fmaxf(fmaf(x0.z - m0.z, r0.z, b0.z), 0.f);
  y0.w = fmaxf(fmaf(x0.w - m0.w, r0.w, b0.w), 0.f);
  y1.x = fmaxf(fmaf(x1.x - m1.x, r1.x, b1.x), 0.f);
  y1.y = fmaxf(fmaf(x1.y - m1.y, r1.y, b1.y), 0.f);
  y1.z = fmaxf(fmaf(x1.z - m1.z, r1.z, b1.z), 0.f);
  y1.w = fmaxf(fmaf(x1.w - m1.w, r1.w, b1.w), 0.f);
  st4(outp + off, y0);
  st4(outp + off + 4, y1);
}

// ---------------------------------------------------------------- pack / convert
// xT hi/lo [(b*128+f)][n] (coalesced writes, strided reads); adj hi/lo;
// w0t hi/lo [o][f]; w2t hi/lo [c][f]; cwt [co][kz*256+ci]; zbuf=0.
__global__ __launch_bounds__(256) void pack_w(
    const float* __restrict__ x, const float* __restrict__ adj,
    const float* __restrict__ gcw, const float* __restrict__ gatw,
    const float* __restrict__ convw,
    u16* __restrict__ xth, u16* __restrict__ xtl,
    u16* __restrict__ adjh, u16* __restrict__ adjl,
    u16* __restrict__ w0th, u16* __restrict__ w0tl,
    u16* __restrict__ w2th, u16* __restrict__ w2tl,
    u16* __restrict__ cwt, u16* __restrict__ zb)
{
  const int idx = blockIdx.x * 256 + threadIdx.x;
  if (idx < 2097152){
    const int bf = idx >> 10, n = idx & 1023;
    const int b = bf >> 7, f = bf & 127;
    const float v = x[((size_t)b * 1024 + n) * 128 + f];
    const u16 hi = f2bf(v);
    xth[idx] = hi; xtl[idx] = f2bf(v - bf2f(hi));
  }
  if (idx < 1048576){
    const float v = adj[idx];
    const u16 hi = f2bf(v);
    adjh[idx] = hi; adjl[idx] = f2bf(v - bf2f(hi));
  }
  if (idx < 32768){
    const int o = idx >> 7, f = idx & 127;
    const float v = gcw[f * 256 + o];
    const u16 hi = f2bf(v);
    w0th[idx] = hi; w0tl[idx] = f2bf(v - bf2f(hi));
  }
  if (idx < 65536){
    const int c = idx >> 8, f = idx & 255;
    const float v = gatw[(c >> 6) * 16384 + f * 64 + (c & 63)];
    const u16 hi = f2bf(v);
    w2th[idx] = hi; w2tl[idx] = f2bf(v - bf2f(hi));
  }
  if (idx < 196608){
    const int co = idx / 768, k = idx - co * 768;
    const int kz = k >> 8, ci = k & 255;
    cwt[idx] = f2bf(convw[co * 768 + ci * 3 + kz]);
  }
  if (idx < 2048) zb[idx] = 0;
}

// ---------------------------------------------------------------- launch
extern "C" void kernel_launch(void* const* d_in, const int* in_sizes, int n_in,
                              void* d_out, int out_size, void* d_ws, size_t ws_size,
                              hipStream_t stream)
{
  const float* x     = (const float*)d_in[0];
  const float* adj   = (const float*)d_in[1];
  const float* gc_w  = (const float*)d_in[2];
  const float* gc_b  = (const float*)d_in[3];
  const float* bn1g  = (const float*)d_in[4];
  const float* bn1b  = (const float*)d_in[5];
  const float* gatw  = (const float*)d_in[6];
  const float* convw = (const float*)d_in[7];
  const float* convb = (const float*)d_in[8];
  const float* bn2g  = (const float*)d_in[9];
  const float* bn2b  = (const float*)d_in[10];
  char* ws  = (char*)d_ws;
  char* out = (char*)d_out;

  // ws layout (bytes), ~25.6 MB high-water. Timeline-checked aliases:
  u16* ax_hi  = (u16*)(ws + 0);              // 4 MB [16384][128]
  u16* ax_lo  = (u16*)(ws + 4194304);        // 4 MB
  u16* adj_hi = (u16*)(ws + 8388608);        // 2 MB (dead after adjx)
  u16* adj_lo = (u16*)(ws + 10485760);       // 2 MB
  u16* xT_hi  = (u16*)(ws + 16777216);       // 4 MB (dead after adjx)
  u16* xT_lo  = (u16*)(ws + 20971520);       // 4 MB
  u16* h_hi   = (u16*)(ws + 0);              // 8 MB (kills ax after bn_apply_split)
  u16* h_lo   = (u16*)(ws + 8388608);        // 8 MB (kills adj)
  u16* hpT    = (u16*)(ws + 16777216);       // 8 MB (kills xT)
  u16* ao     = (u16*)(ws + 0);              // 8 MB (kills h_hi)
  u16* w0th   = (u16*)(ws + 25165824);       // 64 KB
  u16* w0tl   = (u16*)(ws + 25231360);       // 64 KB
  u16* w2th   = (u16*)(ws + 25296896);       // 128 KB
  u16* w2tl   = (u16*)(ws + 25427968);       // 128 KB
  u16* cwt    = (u16*)(ws + 25559040);       // 384 KB
  u16* zbuf   = (u16*)(ws + 25952256);       // 4 KB zeros
  float* P1   = (float*)(ws + 25956352);     // 512 KB bn partial slots (sum | sumsq)
  float* PR1  = (float*)(ws + 26480640);     // 3 KB
  float* PR2  = (float*)(ws + 26484736);     // 3 KB
  u16* g_hi  = (u16*)out;                    // gemm1n out hi (8 MB), dead after bn_apply_split
  u16* g_lo  = (u16*)(out + 8388608);        // gemm1n out lo (8 MB)
  u16* hp_hi = (u16*)out;                    // gemm2 out, dead after flash
  u16* hp_lo = (u16*)(out + 8388608);
  float* y   = (float*)out;                  // gemm3 out -> bn2 in-place -> final

  pack_w<<<8192, 256, 0, stream>>>(x, adj, gc_w, gatw, convw,
                                   xT_hi, xT_lo, adj_hi, adj_lo,
                                   w0th, w0tl, w2th, w2tl, cwt, zbuf);
  // adjx (split): adj @ xT -> ax hi/lo. 64x64 tiles, n on x (XCD owns xT panels).
  adjx_k<<<dim3(32, 16), 256, 0, stream>>>(adj_hi, adj_lo, xT_hi, xT_lo, zbuf,
                                           ax_hi, ax_lo);
  // gemm1n (split): ax @ W0 -> g hi/lo (+gc_b, relu) + BN1 partials. KT=4.
  gemm1n_k<<<dim3(4, 128), 256, 0, stream>>>(ax_hi, ax_lo, w0th, w0tl, zbuf,
                                             g_hi, g_lo, P1, gc_b);
  bn_final<<<1, 256, 0, stream>>>(P1, bn1g, bn1b, PR1);
  bn_apply_split<<<4096, 256, 0, stream>>>(g_hi, g_lo, h_hi, h_lo, PR1);
  // gemm2 (split): h @ w2t -> hp hi/lo + hpT   (128x64 tiles, 512 blocks)
  gemm2_k<<<dim3(4, 128), 256, 0, stream>>>(h_hi, h_lo, w2th, w2tl, zbuf, hp_hi, hp_lo, hpT);
  // flash GAT (512 blocks x 128 q-rows, dbuf 2-phase)
  flash<<<512, 256, 0, stream>>>(hp_hi, hp_lo, hpT, ao);
  // gemm3: im2col(ao) @ cwt -> y fp32 (+conv_b) + BN2 partials
  gemm3_k<<<dim3(4, 128), 256, 0, stream>>>(ao, cwt, zbuf, y, P1, convb);
  bn_final<<<1, 256, 0, stream>>>(P1, bn2g, bn2b, PR2);
  bn_apply<<<2048, 256, 0, stream>>>(y, y, PR2);
}